// Round 12
// baseline (109.879 us; speedup 1.0000x reference)
//
#include <hip/hip_runtime.h>
#include <stdint.h>

typedef unsigned int  u32;
typedef unsigned short u16;

#define B_ROWS 131072
#define P_PRED 64
#define C_CLS  128
#define NPAIR  384               // C*L raw words for dtype detection
#define CAP    32                // max records per predicate (mean 6)
#define RPB    256               // rows per block (4 per thread)
#define TPB    512               // 8 waves; wave g owns predicates [8g, 8g+8)
#define GCAP   104               // record capacity per 8-pred group (mean 48)
#define LOG2E  1.4426950408889634f

#if __has_builtin(__builtin_amdgcn_exp2f)
#define EXP2F(x) __builtin_amdgcn_exp2f(x)
#else
#define EXP2F(x) exp2f(x)
#endif

#if __has_builtin(__builtin_amdgcn_rcpf)
#define RCPF(x) __builtin_amdgcn_rcpf(x)
#else
#define RCPF(x) (1.0f / (x))
#endif

__device__ __forceinline__ float bf16_to_f(u16 u) {
    return __uint_as_float(((u32)u) << 16);
}
__device__ __forceinline__ u16 f_to_bf16(float f) {
    u32 u = __float_as_uint(f);
    u += 0x7FFFu + ((u >> 16) & 1u);   // RNE
    return (u16)(u >> 16);
}
__device__ __forceinline__ u32 pack_bf16x2(float lo, float hi) {
    return (u32)f_to_bf16(lo) | ((u32)f_to_bf16(hi) << 16);
}

// ---------------------------------------------------------------------------
// Fused kernel, quad-row edition. Block = 256 rows, thread owns rows
// (4*lane .. 4*lane+3). Single-sign table E1q[idx][rowquad] (64x64 uint2 =
// 32 KB): ONE ds_read_b64 serves 4 rows (R11 paid 1 DS instr / 2 rows; DS
// instruction count was the ~12 us residual). Negative literals: rcp under a
// SCALAR branch (record words are wave-uniform -> readfirstlane -> s_cbranch).
// Phases: 0) inline prep (R11-validated, scratch aliased into E1q);
// 1) stage E1q; 2) record loop (LDS records, no atomics/readlane-chains/
// s_load chains); 3) direct stores. Grid = 512 -> 2 blocks/CU, 16 waves/CU
// (R8 showed 16 waves is sufficient TLP here). LDS = 39.5 KB. ws UNUSED.
// ---------------------------------------------------------------------------
__global__ __launch_bounds__(TPB, 4)
void ke_fused(const u32* __restrict__ lidx_w,
              const u32* __restrict__ sb_w,
              const u32* __restrict__ w_w,
              const void* __restrict__ atoms_v,
              void* __restrict__ out_v) {
    __shared__ uint2 E1q[P_PRED * 64];        // [slot][rowquad], 32 KB
    __shared__ uint2 srec[8 * GCAP];          // 6656 B
    __shared__ unsigned char cnt8[P_PRED];    // 64 B

    const int tid = threadIdx.x;
    const int lane = tid & 63;
    const int g = __builtin_amdgcn_readfirstlane(tid >> 6);  // 0..7, SGPR
    const int rowBase = blockIdx.x * RPB;

    // ======== phase 0: inline prep (scratch aliased into E1q) ========
    u32*   S     = (u32*)E1q;         // 8192 u32 available; scratch uses 5120
    int*   scnt  = (int*)&S[0];       // [64]
    int*   det   = (int*)&S[64];      // [3]
    int*   sidx  = (int*)&S[128];     // [384]
    int*   ssb   = (int*)&S[512];     // [384]
    u32*   recPk = &S[1024];          // [64][32]
    float* recW  = (float*)&S[3072];  // [64][32]

    if (tid < P_PRED) scnt[tid] = 0;
    if (tid < 3) det[tid] = 1;
    __syncthreads();
    if (tid < NPAIR / 2) {
        if (lidx_w[2 * tid + 1] != 0u) det[0] = 0;   // benign race (all write 0)
        if (sb_w[2 * tid + 1]   != 0u) det[1] = 0;
    }
    if (tid == 0 && (w_w[0] & 0xFFFFu) == 0u) det[2] = 0;
    __syncthreads();
    if (tid < NPAIR) {
        sidx[tid] = (int)(det[0] ? lidx_w[2 * tid] : lidx_w[tid]);
        ssb[tid]  = (int)(det[1] ? sb_w[2 * tid]   : sb_w[tid]);
    }
    __syncthreads();
    const bool bf16m = (det[2] != 0);            // latch before S is reused
    if (tid < NPAIR) {
        const int c = tid / 3;
        const int l = tid - c * 3;
        const int base = c * 3;
        const int o1 = base + (l == 0 ? 1 : 0);
        const int o2 = base + (l == 2 ? 1 : 2);
        const int p = sidx[tid];
        const int slot = atomicAdd(&scnt[p], 1); // prep-only LDS atomics: fine
        float wraw = bf16m ? bf16_to_f((u16)(w_w[c / 2] >> ((c & 1) * 16)))
                           : __uint_as_float(w_w[c]);
        float wc = fminf(fmaxf(wraw, 0.0f), 500.0f);
        if (slot < CAP) {
            u32 s1 = 2u * (u32)sidx[o1] + (ssb[o1] ? 0u : 1u);
            u32 s2 = 2u * (u32)sidx[o2] + (ssb[o2] ? 0u : 1u);
            recPk[p * CAP + slot] = (ssb[tid] ? 0u : 1u) | (s1 << 8) | (s2 << 16);
            recW[p * CAP + slot]  = ssb[tid] ? wc : -wc;
        }
    }
    __syncthreads();
    if (tid < P_PRED) {
        const int p = tid;
        const int gg = p >> 3;
        const int n = min(scnt[p], CAP);
        int off = 0;
        for (int pb = gg * 8; pb < p; ++pb) off += min(scnt[pb], CAP);
        int ncl = 0;
        for (int j = 0; j < n; ++j) {
            if (off + j < GCAP) {
                srec[gg * GCAP + off + j] =
                    make_uint2(recPk[p * CAP + j], __float_as_uint(recW[p * CAP + j]));
                ++ncl;
            }
        }
        cnt8[p] = (unsigned char)ncl;
    }
    __syncthreads();   // srec/cnt8 ready; prep scratch dead

    // ======== phase 1: stage E1q (4 rows per entry, 8 ds_write_b64) ========
    {
        const int a = tid & 63;                  // row quad
        const int c0 = (tid >> 6) * 8;           // 8-atom chunk
        if (bf16m) {
            const u16* gp = (const u16*)atoms_v + (size_t)(rowBase + 4 * a) * P_PRED + c0;
            uint4 v0 = *(const uint4*)gp;                // row 4a
            uint4 v1 = *(const uint4*)(gp + P_PRED);     // row 4a+1
            uint4 v2 = *(const uint4*)(gp + 2 * P_PRED); // row 4a+2
            uint4 v3 = *(const uint4*)(gp + 3 * P_PRED); // row 4a+3
            u32 w0[4] = {v0.x, v0.y, v0.z, v0.w};
            u32 w1[4] = {v1.x, v1.y, v1.z, v1.w};
            u32 w2[4] = {v2.x, v2.y, v2.z, v2.w};
            u32 w3[4] = {v3.x, v3.y, v3.z, v3.w};
#pragma unroll
            for (int k = 0; k < 4; ++k) {
                float l0 = EXP2F(__uint_as_float(w0[k] << 16) * LOG2E);
                float l1 = EXP2F(__uint_as_float(w1[k] << 16) * LOG2E);
                float l2 = EXP2F(__uint_as_float(w2[k] << 16) * LOG2E);
                float l3 = EXP2F(__uint_as_float(w3[k] << 16) * LOG2E);
                float h0 = EXP2F(__uint_as_float(w0[k] & 0xFFFF0000u) * LOG2E);
                float h1 = EXP2F(__uint_as_float(w1[k] & 0xFFFF0000u) * LOG2E);
                float h2 = EXP2F(__uint_as_float(w2[k] & 0xFFFF0000u) * LOG2E);
                float h3 = EXP2F(__uint_as_float(w3[k] & 0xFFFF0000u) * LOG2E);
                E1q[(c0 + 2 * k)     * 64 + a] =
                    make_uint2(pack_bf16x2(l0, l1), pack_bf16x2(l2, l3));
                E1q[(c0 + 2 * k + 1) * 64 + a] =
                    make_uint2(pack_bf16x2(h0, h1), pack_bf16x2(h2, h3));
            }
        } else {
            const float* gp = (const float*)atoms_v + (size_t)(rowBase + 4 * a) * P_PRED + c0;
            float x0[8], x1[8], x2[8], x3[8];
            *(float4*)&x0[0] = *(const float4*)gp;
            *(float4*)&x0[4] = *(const float4*)(gp + 4);
            *(float4*)&x1[0] = *(const float4*)(gp + P_PRED);
            *(float4*)&x1[4] = *(const float4*)(gp + P_PRED + 4);
            *(float4*)&x2[0] = *(const float4*)(gp + 2 * P_PRED);
            *(float4*)&x2[4] = *(const float4*)(gp + 2 * P_PRED + 4);
            *(float4*)&x3[0] = *(const float4*)(gp + 3 * P_PRED);
            *(float4*)&x3[4] = *(const float4*)(gp + 3 * P_PRED + 4);
#pragma unroll
            for (int m = 0; m < 8; ++m) {
                float e0 = EXP2F(x0[m] * LOG2E);
                float e1 = EXP2F(x1[m] * LOG2E);
                float e2 = EXP2F(x2[m] * LOG2E);
                float e3 = EXP2F(x3[m] * LOG2E);
                E1q[(c0 + m) * 64 + a] =
                    make_uint2(pack_bf16x2(e0, e1), pack_bf16x2(e2, e3));
            }
        }
    }
    __syncthreads();

    // ======== phase 2: record loop (quad rows) ========
    float ac[8][4];
    int j = g * GCAP;                      // stream cursor

#pragma unroll
    for (int pp = 0; pp < 8; ++pp) {
        const int p = g * 8 + pp;                        // wave-uniform
        const uint2 eq = E1q[p * 64 + lane];             // ds_read_b64
        float ep[4] = {__uint_as_float(eq.x << 16),
                       __uint_as_float(eq.x & 0xFFFF0000u),
                       __uint_as_float(eq.y << 16),
                       __uint_as_float(eq.y & 0xFFFF0000u)};
        float en[4] = {RCPF(ep[0]), RCPF(ep[1]), RCPF(ep[2]), RCPF(ep[3])};
        const int n = (int)cnt8[p];
        float a0[4] = {0.0f, 0.0f, 0.0f, 0.0f};

        for (int e = 0; e < n; ++e, ++j) {
            const uint2 rec = srec[j];                   // b64 broadcast
            // record words are wave-uniform -> move to scalar regs
            const u32 pk = (u32)__builtin_amdgcn_readfirstlane((int)rec.x);
            const float sw = __uint_as_float(
                (u32)__builtin_amdgcn_readfirstlane((int)rec.y));
            const u32 sl1 = (pk >> 8) & 255u;
            const u32 sl2 = (pk >> 16) & 255u;
            const uint2 q1 = E1q[(int)(sl1 >> 1) * 64 + lane];   // b64
            const uint2 q2 = E1q[(int)(sl2 >> 1) * 64 + lane];   // b64
            float s1[4] = {__uint_as_float(q1.x << 16),
                           __uint_as_float(q1.x & 0xFFFF0000u),
                           __uint_as_float(q1.y << 16),
                           __uint_as_float(q1.y & 0xFFFF0000u)};
            float s2[4] = {__uint_as_float(q2.x << 16),
                           __uint_as_float(q2.x & 0xFFFF0000u),
                           __uint_as_float(q2.y << 16),
                           __uint_as_float(q2.y & 0xFFFF0000u)};
            if (sl1 & 1u) {                              // scalar branch
#pragma unroll
                for (int r = 0; r < 4; ++r) s1[r] = RCPF(s1[r]);
            }
            if (sl2 & 1u) {
#pragma unroll
                for (int r = 0; r < 4; ++r) s2[r] = RCPF(s2[r]);
            }
#pragma unroll
            for (int r = 0; r < 4; ++r) {
                const float ssr = (pk & 1u) ? en[r] : ep[r];
                const float t = RCPF(ssr + s1[r] + s2[r]);
                a0[r] = fmaf(sw * ssr, t, a0[r]);
            }
        }
#pragma unroll
        for (int r = 0; r < 4; ++r) ac[pp][r] = a0[r];
    }

    // ======== phase 3: direct stores (4 rows x 8 preds per thread) ========
    const int row0 = rowBase + 4 * lane;
    if (bf16m) {
#pragma unroll
        for (int r = 0; r < 4; ++r) {
            uint4 o;
            o.x = pack_bf16x2(ac[0][r], ac[1][r]);
            o.y = pack_bf16x2(ac[2][r], ac[3][r]);
            o.z = pack_bf16x2(ac[4][r], ac[5][r]);
            o.w = pack_bf16x2(ac[6][r], ac[7][r]);
            *(uint4*)((u16*)out_v + (size_t)(row0 + r) * P_PRED + g * 8) = o;
        }
    } else {
#pragma unroll
        for (int r = 0; r < 4; ++r) {
            float* op = (float*)out_v + (size_t)(row0 + r) * P_PRED + g * 8;
            *(float4*)(op)     = make_float4(ac[0][r], ac[1][r], ac[2][r], ac[3][r]);
            *(float4*)(op + 4) = make_float4(ac[4][r], ac[5][r], ac[6][r], ac[7][r]);
        }
    }
}

extern "C" void kernel_launch(void* const* d_in, const int* in_sizes, int n_in,
                              void* d_out, int out_size, void* d_ws, size_t ws_size,
                              hipStream_t stream_h) {
    const u32* clause_weights = (const u32*)d_in[1]; // bf16 or f32 [128]
    const u32* literal_idx    = (const u32*)d_in[2]; // int32 or int64 [128,3]
    const u32* sign_bits      = (const u32*)d_in[3]; // int32 or int64 [128,3]
    (void)d_ws; (void)ws_size;                       // workspace unused

    ke_fused<<<B_ROWS / RPB, TPB, 0, stream_h>>>(literal_idx, sign_bits,
                                                 clause_weights, d_in[0],
                                                 d_out);
}

// Round 13
// 106.494 us; speedup vs baseline: 1.0318x; 1.0318x over previous
//
#include <hip/hip_runtime.h>
#include <stdint.h>

typedef unsigned int  u32;
typedef unsigned short u16;

#define B_ROWS 131072
#define P_PRED 64
#define C_CLS  128
#define NPAIR  384               // C*L raw words for dtype detection
#define CAP    32                // max records per predicate (mean 6)
#define RPB    256               // rows per block (4 per thread)
#define TPB    512               // 8 waves; wave g owns predicates [8g, 8g+8)
#define TSTR   34                // u32 stride of transpose buffer rows
#define LOG2E  1.4426950408889634f

#if __has_builtin(__builtin_amdgcn_exp2f)
#define EXP2F(x) __builtin_amdgcn_exp2f(x)
#else
#define EXP2F(x) exp2f(x)
#endif

#if __has_builtin(__builtin_amdgcn_rcpf)
#define RCPF(x) __builtin_amdgcn_rcpf(x)
#else
#define RCPF(x) (1.0f / (x))
#endif

__device__ __forceinline__ float bf16_to_f(u16 u) {
    return __uint_as_float(((u32)u) << 16);
}
__device__ __forceinline__ u16 f_to_bf16(float f) {
    u32 u = __float_as_uint(f);
    u += 0x7FFFu + ((u >> 16) & 1u);   // RNE
    return (u16)(u >> 16);
}
__device__ __forceinline__ u32 pack_bf16x2(float lo, float hi) {
    return (u32)f_to_bf16(lo) | ((u32)f_to_bf16(hi) << 16);
}
__device__ __forceinline__ float blo(u32 v) { return __uint_as_float(v << 16); }
__device__ __forceinline__ float bhi(u32 v) { return __uint_as_float(v & 0xFFFF0000u); }

// ---------------------------------------------------------------------------
// Prep (R8-validated): dtype detection + per-predicate CSR of 4-dword recs:
//   r0 = selfNeg; r1 = 2*idx1+neg1; r2 = 2*idx2+neg2 (slots into both-signs
//   table); r3 = bits of sign_self * clamp(w,0,500).
// ---------------------------------------------------------------------------
__global__ void ke_prep(const u32* __restrict__ lidx_w,
                        const u32* __restrict__ sb_w,
                        const u32* __restrict__ w_w,
                        u32* __restrict__ recs,     // [64*CAP*4] dwords
                        int* __restrict__ cnts,     // [64]
                        u32* __restrict__ flags) {  // [1]: 1 = bf16 floats
    __shared__ int scnt[P_PRED];
    __shared__ int sidx[NPAIR];
    __shared__ int ssb[NPAIR];
    __shared__ int det[3];
    const int t = threadIdx.x;
    if (t < P_PRED) scnt[t] = 0;
    if (t < 3) det[t] = 1;
    __syncthreads();
    if (t < NPAIR / 2) {
        if (lidx_w[2 * t + 1] != 0u) det[0] = 0;   // benign race (all write 0)
        if (sb_w[2 * t + 1]   != 0u) det[1] = 0;
    }
    if (t == 0 && (w_w[0] & 0xFFFFu) == 0u) det[2] = 0;
    __syncthreads();
    if (t < NPAIR) {
        sidx[t] = (int)(det[0] ? lidx_w[2 * t] : lidx_w[t]);
        ssb[t]  = (int)(det[1] ? sb_w[2 * t]   : sb_w[t]);
    }
    __syncthreads();
    if (t < NPAIR) {
        const int c = t / 3;
        const int l = t - c * 3;
        const int base = c * 3;
        const int o1 = base + (l == 0 ? 1 : 0);
        const int o2 = base + (l == 2 ? 1 : 2);
        const int p = sidx[t];
        const int slot = atomicAdd(&scnt[p], 1);   // prep-only LDS atomics: fine
        float wraw = det[2] ? bf16_to_f((u16)(w_w[c / 2] >> ((c & 1) * 16)))
                            : __uint_as_float(w_w[c]);
        float wc = fminf(fmaxf(wraw, 0.0f), 500.0f);
        if (slot < CAP) {
            u32* r = recs + (p * CAP + slot) * 4;
            r[0] = ssb[t] ? 0u : 1u;
            r[1] = 2u * (u32)sidx[o1] + (ssb[o1] ? 0u : 1u);
            r[2] = 2u * (u32)sidx[o2] + (ssb[o2] ? 0u : 1u);
            r[3] = __float_as_uint(ssb[t] ? wc : -wc);
        }
    }
    __syncthreads();
    if (t < P_PRED) cnts[t] = min(scnt[t], CAP);
    if (t == 0) flags[0] = (u32)det[2];
}

// ---------------------------------------------------------------------------
// Main, quad-row both-signs edition. Thread owns rows (4*lane..4*lane+3).
// E2q[slot 0..127][quad 0..63] uint2 = bf16 x4 rows = 64 KB EXACT (R8
// precedent for 64 KB static LDS). Per record: 2x ds_read_b64 serve 4 rows,
// ZERO transcendentals beyond 4 sum-rcps (trans shares the VALU pipe at 1/4
// rate -- keep it out of the loop). Records: R8's wave-uniform s_load CSR
// (no LDS room left; R8 showed this is fine). Epilogue: transpose through
// the dead table region (stride-34 u32, aligned b64) -> coalesced 64 B/
// thread stores (R12 measured 73 MB WRITE for 16.8 logical = ~10 us bug).
// Grid 512, 2 blocks/CU x 8 waves = 16 waves/CU.
// ---------------------------------------------------------------------------
__global__ __launch_bounds__(TPB, 4)
void ke_main(const void* __restrict__ atoms_v,
             const u32* __restrict__ recs_u,
             const int* __restrict__ cnts,
             const u32* __restrict__ flags,
             void* __restrict__ out_v) {
    __shared__ uint2 E2q[128 * 64];    // 64 KB; epilogue reuses as transpose
    const int tid = threadIdx.x;
    const int lane = tid & 63;
    const int g = __builtin_amdgcn_readfirstlane(tid >> 6);  // 0..7, SGPR
    const int rowBase = blockIdx.x * RPB;
    const bool bf16m = (flags[0] != 0u);

    // ---- stage: thread = (row quad a = tid&63, 8-atom chunk = (tid>>6)*8)
    {
        const int a = tid & 63;
        const int c0 = (tid >> 6) * 8;
        if (bf16m) {
            const u16* gp = (const u16*)atoms_v + (size_t)(rowBase + 4 * a) * P_PRED + c0;
            uint4 v0 = *(const uint4*)gp;
            uint4 v1 = *(const uint4*)(gp + P_PRED);
            uint4 v2 = *(const uint4*)(gp + 2 * P_PRED);
            uint4 v3 = *(const uint4*)(gp + 3 * P_PRED);
            u32 w0[4] = {v0.x, v0.y, v0.z, v0.w};
            u32 w1[4] = {v1.x, v1.y, v1.z, v1.w};
            u32 w2[4] = {v2.x, v2.y, v2.z, v2.w};
            u32 w3[4] = {v3.x, v3.y, v3.z, v3.w};
#pragma unroll
            for (int k = 0; k < 4; ++k) {
                // atom m = c0+2k (low halves), m+1 (high halves); rows 4a..4a+3
                float l0 = EXP2F(blo(w0[k]) * LOG2E);
                float l1 = EXP2F(blo(w1[k]) * LOG2E);
                float l2 = EXP2F(blo(w2[k]) * LOG2E);
                float l3 = EXP2F(blo(w3[k]) * LOG2E);
                float h0 = EXP2F(bhi(w0[k]) * LOG2E);
                float h1 = EXP2F(bhi(w1[k]) * LOG2E);
                float h2 = EXP2F(bhi(w2[k]) * LOG2E);
                float h3 = EXP2F(bhi(w3[k]) * LOG2E);
                const int m = c0 + 2 * k;
                E2q[(2 * m)     * 64 + a] = make_uint2(pack_bf16x2(l0, l1), pack_bf16x2(l2, l3));
                E2q[(2 * m + 1) * 64 + a] = make_uint2(pack_bf16x2(RCPF(l0), RCPF(l1)),
                                                       pack_bf16x2(RCPF(l2), RCPF(l3)));
                E2q[(2 * m + 2) * 64 + a] = make_uint2(pack_bf16x2(h0, h1), pack_bf16x2(h2, h3));
                E2q[(2 * m + 3) * 64 + a] = make_uint2(pack_bf16x2(RCPF(h0), RCPF(h1)),
                                                       pack_bf16x2(RCPF(h2), RCPF(h3)));
            }
        } else {
            const float* gp = (const float*)atoms_v + (size_t)(rowBase + 4 * a) * P_PRED + c0;
            float x0[8], x1[8], x2[8], x3[8];
            *(float4*)&x0[0] = *(const float4*)gp;
            *(float4*)&x0[4] = *(const float4*)(gp + 4);
            *(float4*)&x1[0] = *(const float4*)(gp + P_PRED);
            *(float4*)&x1[4] = *(const float4*)(gp + P_PRED + 4);
            *(float4*)&x2[0] = *(const float4*)(gp + 2 * P_PRED);
            *(float4*)&x2[4] = *(const float4*)(gp + 2 * P_PRED + 4);
            *(float4*)&x3[0] = *(const float4*)(gp + 3 * P_PRED);
            *(float4*)&x3[4] = *(const float4*)(gp + 3 * P_PRED + 4);
#pragma unroll
            for (int m = 0; m < 8; ++m) {
                float e0 = EXP2F(x0[m] * LOG2E);
                float e1 = EXP2F(x1[m] * LOG2E);
                float e2 = EXP2F(x2[m] * LOG2E);
                float e3 = EXP2F(x3[m] * LOG2E);
                E2q[(2 * (c0 + m))     * 64 + a] = make_uint2(pack_bf16x2(e0, e1), pack_bf16x2(e2, e3));
                E2q[(2 * (c0 + m) + 1) * 64 + a] = make_uint2(pack_bf16x2(RCPF(e0), RCPF(e1)),
                                                              pack_bf16x2(RCPF(e2), RCPF(e3)));
            }
        }
    }
    __syncthreads();

    // ---- record loop: 8 independent per-pred loops, records via s_load
    float ac[8][4];
#pragma unroll
    for (int pp = 0; pp < 8; ++pp) {
        const int p = g * 8 + pp;                        // wave-uniform
        const uint2 eq = E2q[(2 * p)     * 64 + lane];   // self +, quad
        const uint2 nq = E2q[(2 * p + 1) * 64 + lane];   // self -, quad
        const float ep[4] = {blo(eq.x), bhi(eq.x), blo(eq.y), bhi(eq.y)};
        const float en[4] = {blo(nq.x), bhi(nq.x), blo(nq.y), bhi(nq.y)};
        const int n = min(cnts[p], CAP);                 // s_load
        const u32* rp = recs_u + p * CAP * 4;
        float a0[4] = {0.f, 0.f, 0.f, 0.f};
        float a1[4] = {0.f, 0.f, 0.f, 0.f};

#define REC_BODY(EIDX, A)                                                     \
        {                                                                     \
            const u32* r = rp + (EIDX) * 4;            /* s_load_dwordx4 */   \
            const u32 sN = r[0];                                              \
            const int s1 = (int)r[1];                                         \
            const int s2 = (int)r[2];                                         \
            const float sw = __uint_as_float(r[3]);                           \
            const uint2 q1 = E2q[s1 * 64 + lane];      /* ds_read_b64 */      \
            const uint2 q2 = E2q[s2 * 64 + lane];      /* ds_read_b64 */      \
            const float x1v[4] = {blo(q1.x), bhi(q1.x), blo(q1.y), bhi(q1.y)};\
            const float x2v[4] = {blo(q2.x), bhi(q2.x), blo(q2.y), bhi(q2.y)};\
            _Pragma("unroll")                                                 \
            for (int rr = 0; rr < 4; ++rr) {                                  \
                const float ss = sN ? en[rr] : ep[rr]; /* uniform cndmask */  \
                const float t = RCPF(ss + x1v[rr] + x2v[rr]);                 \
                A[rr] = fmaf(sw * ss, t, A[rr]);                              \
            }                                                                 \
        }

        int e = 0;
        for (; e + 1 < n; e += 2) {        // unroll x2, dual accumulators
            REC_BODY(e, a0)
            REC_BODY(e + 1, a1)
        }
        if (e < n) REC_BODY(e, a0)
#undef REC_BODY
#pragma unroll
        for (int rr = 0; rr < 4; ++rr) ac[pp][rr] = a0[rr] + a1[rr];
    }

    // ---- epilogue
    if (bf16m) {
        __syncthreads();                   // all waves done reading E2q
        u32* T = (u32*)E2q;                // [256 rows][TSTR u32], 34.8 KB
#pragma unroll
        for (int rr = 0; rr < 4; ++rr) {
            const int row = 4 * lane + rr;
            u32* dst = &T[row * TSTR + g * 4];
            *(uint2*)dst       = make_uint2(pack_bf16x2(ac[0][rr], ac[1][rr]),
                                            pack_bf16x2(ac[2][rr], ac[3][rr]));
            *(uint2*)(dst + 2) = make_uint2(pack_bf16x2(ac[4][rr], ac[5][rr]),
                                            pack_bf16x2(ac[6][rr], ac[7][rr]));
        }
        __syncthreads();
        const int row = tid >> 1;
        const int cb = (tid & 1) * 16;
        const u32* src = &T[row * TSTR + cb];
        u32 buf[16];
#pragma unroll
        for (int i = 0; i < 16; i += 2) {              // 8-B aligned b64 reads
            uint2 v = *(const uint2*)(src + i);
            buf[i] = v.x; buf[i + 1] = v.y;
        }
        u16* op = (u16*)out_v + (size_t)(rowBase + row) * P_PRED + cb * 2;
#pragma unroll
        for (int i = 0; i < 4; ++i)                    // 64 B/thread, coalesced
            *(uint4*)(op + i * 8) = make_uint4(buf[4*i], buf[4*i+1], buf[4*i+2], buf[4*i+3]);
    } else {
        const int row0 = rowBase + 4 * lane;
#pragma unroll
        for (int rr = 0; rr < 4; ++rr) {
            float* op = (float*)out_v + (size_t)(row0 + rr) * P_PRED + g * 8;
            *(float4*)(op)     = make_float4(ac[0][rr], ac[1][rr], ac[2][rr], ac[3][rr]);
            *(float4*)(op + 4) = make_float4(ac[4][rr], ac[5][rr], ac[6][rr], ac[7][rr]);
        }
    }
}

extern "C" void kernel_launch(void* const* d_in, const int* in_sizes, int n_in,
                              void* d_out, int out_size, void* d_ws, size_t ws_size,
                              hipStream_t stream_h) {
    const u32* clause_weights = (const u32*)d_in[1]; // bf16 or f32 [128]
    const u32* literal_idx    = (const u32*)d_in[2]; // int32 or int64 [128,3]
    const u32* sign_bits      = (const u32*)d_in[3]; // int32 or int64 [128,3]

    u32* recs  = (u32*)d_ws;                              // 64*32*16 B = 32 KiB
    int* cnts  = (int*)((char*)d_ws + P_PRED * CAP * 16); // 256 B
    u32* flags = (u32*)((char*)d_ws + P_PRED * CAP * 16 + 256);

    ke_prep<<<1, NPAIR, 0, stream_h>>>(literal_idx, sign_bits, clause_weights,
                                       recs, cnts, flags);
    ke_main<<<B_ROWS / RPB, TPB, 0, stream_h>>>(d_in[0], recs, cnts, flags,
                                                d_out);
}

// Round 14
// 103.690 us; speedup vs baseline: 1.0597x; 1.0270x over previous
//
#include <hip/hip_runtime.h>
#include <stdint.h>

typedef unsigned int  u32;
typedef unsigned short u16;

#define B_ROWS 131072
#define P_PRED 64
#define C_CLS  128
#define NPAIR  384               // C*L raw words for dtype detection
#define CAP    32                // max records per predicate (mean 6)
#define RPB    128               // rows per block (2 rows per thread)
#define TPB    512               // 8 waves; wave g owns predicates [8g, 8g+8)
#define GCAP   104               // record capacity per 8-pred group (mean 48)
#define LOG2E  1.4426950408889634f

#if __has_builtin(__builtin_amdgcn_exp2f)
#define EXP2F(x) __builtin_amdgcn_exp2f(x)
#else
#define EXP2F(x) exp2f(x)
#endif

#if __has_builtin(__builtin_amdgcn_rcpf)
#define RCPF(x) __builtin_amdgcn_rcpf(x)
#else
#define RCPF(x) (1.0f / (x))
#endif

__device__ __forceinline__ float bf16_to_f(u16 u) {
    return __uint_as_float(((u32)u) << 16);
}
__device__ __forceinline__ u16 f_to_bf16(float f) {
    u32 u = __float_as_uint(f);
    u += 0x7FFFu + ((u >> 16) & 1u);   // RNE
    return (u16)(u >> 16);
}
__device__ __forceinline__ u32 pack_bf16x2(float lo, float hi) {
    return (u32)f_to_bf16(lo) | ((u32)f_to_bf16(hi) << 16);
}
__device__ __forceinline__ float blo(u32 v) { return __uint_as_float(v << 16); }
__device__ __forceinline__ float bhi(u32 v) { return __uint_as_float(v & 0xFFFF0000u); }

// ---------------------------------------------------------------------------
// Fused kernel (R11 base = session best, 102.6 us) + depth-1 software
// prefetch in the record loop. Phases:
//   0: inline prep (scratch aliased into table LDS) — dtype detect, CSR,
//      per-group sorted record streams srec + byte counts. srec is PADDED
//      (+8) so the loop's one-past-end prefetch is branch-free and safe.
//   1: stage bf16 both-signs table E2[slot][row] (128x128 u16 = 32 KB),
//      paired-row b32 writes.
//   2: record loop, software-pipelined: record j+1's srec + 2 table reads
//      issue BEFORE record j's arithmetic (attacks exposed lgkmcnt latency,
//      the last un-attacked component of the ~30 us kernel residual).
//   3: direct stores (R9/R11 epilogue; transpose variants regressed).
// LDS = 32 KB + 6.7 KB -> 4 blocks/CU x 8 waves = 32 waves/CU. ws UNUSED.
// ---------------------------------------------------------------------------
__global__ __launch_bounds__(TPB, 8)
void ke_fused(const u32* __restrict__ lidx_w,
              const u32* __restrict__ sb_w,
              const u32* __restrict__ w_w,
              const void* __restrict__ atoms_v,
              void* __restrict__ out_v) {
    __shared__ u32 S[8192];                   // 32 KB: prep scratch, then E2
    __shared__ uint2 srec[8 * GCAP + 8];      // 6720 B (padded for prefetch)
    __shared__ unsigned char cnt8[P_PRED];    // 64 B
    u16* E2 = (u16*)S;                        // [slot][128 rows] bf16

    const int tid = threadIdx.x;
    const int lane = tid & 63;
    const int g = __builtin_amdgcn_readfirstlane(tid >> 6);  // 0..7, SGPR
    const int rowBase = blockIdx.x * RPB;

    // ======== phase 0: inline prep (scratch aliased into S) ========
    int*   scnt  = (int*)&S[0];       // [64]
    int*   det   = (int*)&S[64];      // [3]
    int*   sidx  = (int*)&S[128];     // [384]
    int*   ssb   = (int*)&S[512];     // [384]
    u32*   recPk = &S[1024];          // [64][32]
    float* recW  = (float*)&S[3072];  // [64][32]

    if (tid < P_PRED) scnt[tid] = 0;
    if (tid < 3) det[tid] = 1;
    __syncthreads();
    if (tid < NPAIR / 2) {
        if (lidx_w[2 * tid + 1] != 0u) det[0] = 0;   // benign race (all write 0)
        if (sb_w[2 * tid + 1]   != 0u) det[1] = 0;
    }
    if (tid == 0 && (w_w[0] & 0xFFFFu) == 0u) det[2] = 0;
    __syncthreads();
    if (tid < NPAIR) {
        sidx[tid] = (int)(det[0] ? lidx_w[2 * tid] : lidx_w[tid]);
        ssb[tid]  = (int)(det[1] ? sb_w[2 * tid]   : sb_w[tid]);
    }
    __syncthreads();
    const bool bf16m = (det[2] != 0);            // latch before S is reused
    if (tid < NPAIR) {
        const int c = tid / 3;
        const int l = tid - c * 3;
        const int base = c * 3;
        const int o1 = base + (l == 0 ? 1 : 0);
        const int o2 = base + (l == 2 ? 1 : 2);
        const int p = sidx[tid];
        const int slot = atomicAdd(&scnt[p], 1); // prep-only LDS atomics: fine
        float wraw = bf16m ? bf16_to_f((u16)(w_w[c / 2] >> ((c & 1) * 16)))
                           : __uint_as_float(w_w[c]);
        float wc = fminf(fmaxf(wraw, 0.0f), 500.0f);
        if (slot < CAP) {
            u32 s1 = 2u * (u32)sidx[o1] + (ssb[o1] ? 0u : 1u);
            u32 s2 = 2u * (u32)sidx[o2] + (ssb[o2] ? 0u : 1u);
            recPk[p * CAP + slot] = (ssb[tid] ? 0u : 1u) | (s1 << 8) | (s2 << 16);
            recW[p * CAP + slot]  = ssb[tid] ? wc : -wc;
        }
    }
    __syncthreads();
    if (tid < P_PRED) {
        const int p = tid;
        const int gg = p >> 3;
        const int n = min(scnt[p], CAP);
        int off = 0;
        for (int pb = gg * 8; pb < p; ++pb) off += min(scnt[pb], CAP);
        int ncl = 0;
        for (int j = 0; j < n; ++j) {
            if (off + j < GCAP) {
                srec[gg * GCAP + off + j] =
                    make_uint2(recPk[p * CAP + j], __float_as_uint(recW[p * CAP + j]));
                ++ncl;
            }
        }
        cnt8[p] = (unsigned char)ncl;
    }
    if (tid < 8) srec[8 * GCAP + tid] = make_uint2(0u, 0u);  // prefetch pad
    __syncthreads();   // srec/cnt8 ready; prep scratch dead

    // ======== phase 1: stage E2 (paired-row b32 writes) ========
    {
        const int a = tid & 63;                  // row pair (2a, 2a+1)
        const int c0 = (tid >> 6) * 8;           // 8-atom chunk
        if (bf16m) {
            const u16* gp0 = (const u16*)atoms_v + (size_t)(rowBase + 2 * a) * P_PRED + c0;
            uint4 v0 = *(const uint4*)gp0;            // row 2a
            uint4 v1 = *(const uint4*)(gp0 + P_PRED); // row 2a+1
            u32 w0[4] = {v0.x, v0.y, v0.z, v0.w};
            u32 w1[4] = {v1.x, v1.y, v1.z, v1.w};
#pragma unroll
            for (int k = 0; k < 4; ++k) {
                float xl0 = blo(w0[k]) * LOG2E;
                float xh0 = bhi(w0[k]) * LOG2E;
                float xl1 = blo(w1[k]) * LOG2E;
                float xh1 = bhi(w1[k]) * LOG2E;
                float el0 = EXP2F(xl0), eh0 = EXP2F(xh0);
                float el1 = EXP2F(xl1), eh1 = EXP2F(xh1);
                const int m = c0 + 2 * k;
                S[(2 * m)     * 64 + a] = pack_bf16x2(el0, el1);
                S[(2 * m + 1) * 64 + a] = pack_bf16x2(RCPF(el0), RCPF(el1));
                S[(2 * m + 2) * 64 + a] = pack_bf16x2(eh0, eh1);
                S[(2 * m + 3) * 64 + a] = pack_bf16x2(RCPF(eh0), RCPF(eh1));
            }
        } else {
            const float* gp0 = (const float*)atoms_v + (size_t)(rowBase + 2 * a) * P_PRED + c0;
            float4 u0 = *(const float4*)gp0;
            float4 u1 = *(const float4*)(gp0 + 4);
            float4 d0 = *(const float4*)(gp0 + P_PRED);
            float4 d1 = *(const float4*)(gp0 + P_PRED + 4);
            float r0[8] = {u0.x, u0.y, u0.z, u0.w, u1.x, u1.y, u1.z, u1.w};
            float r1[8] = {d0.x, d0.y, d0.z, d0.w, d1.x, d1.y, d1.z, d1.w};
#pragma unroll
            for (int k = 0; k < 8; ++k) {
                float e0 = EXP2F(r0[k] * LOG2E);
                float e1 = EXP2F(r1[k] * LOG2E);
                const int m = c0 + k;
                S[(2 * m)     * 64 + a] = pack_bf16x2(e0, e1);
                S[(2 * m + 1) * 64 + a] = pack_bf16x2(RCPF(e0), RCPF(e1));
            }
        }
    }
    __syncthreads();

    // ======== phase 2: record loop, depth-1 software prefetch ========
    const int q2 = 2 * lane;               // u16 row index of this row pair
    float2 acc[8];
    int j = g * GCAP;                      // stream cursor

#pragma unroll
    for (int pp = 0; pp < 8; ++pp) {
        const int p = g * 8 + pp;                        // wave-uniform
        const u32 eppv = *(const u32*)&E2[(2 * p)     * RPB + q2];
        const u32 epnv = *(const u32*)&E2[(2 * p + 1) * RPB + q2];
        const float eppx = blo(eppv), eppy = bhi(eppv);
        const float epnx = blo(epnv), epny = bhi(epnv);
        const int n = __builtin_amdgcn_readfirstlane((int)cnt8[p]);  // SGPR
        float2 a = make_float2(0.0f, 0.0f);

        // prime the pipeline: record j's stream word + table reads in flight
        uint2 rc = srec[j];
        u32 pk  = rc.x;
        u32 swb = rc.y;
        u32 v1 = *(const u32*)&E2[(int)((pk >> 8)  & 255u) * RPB + q2];
        u32 v2 = *(const u32*)&E2[(int)((pk >> 16) & 255u) * RPB + q2];

        for (int e = 0; e < n; ++e) {
            // capture current record
            const u32 pk_c = pk;
            const float sw = __uint_as_float(swb);
            const u32 v1_c = v1, v2_c = v2;
            // issue NEXT record's loads before current arithmetic
            ++j;
            rc = srec[j];                  // padded: safe one-past-end
            pk  = rc.x;
            swb = rc.y;
            v1 = *(const u32*)&E2[(int)((pk >> 8)  & 255u) * RPB + q2];
            v2 = *(const u32*)&E2[(int)((pk >> 16) & 255u) * RPB + q2];
            // current record arithmetic (overlaps next record's lgkmcnt)
            const float ssx = (pk_c & 1u) ? epnx : eppx;
            const float ssy = (pk_c & 1u) ? epny : eppy;
            const float s1x = blo(v1_c), s1y = bhi(v1_c);
            const float s2x = blo(v2_c), s2y = bhi(v2_c);
            const float tx = RCPF(ssx + s1x + s2x);
            const float ty = RCPF(ssy + s1y + s2y);
            a.x = fmaf(sw * ssx, tx, a.x);
            a.y = fmaf(sw * ssy, ty, a.y);
        }
        acc[pp] = a;
    }

    // ======== phase 3: direct stores ========
    if (bf16m) {
        u16* op0 = (u16*)out_v + (size_t)(rowBase + q2) * P_PRED + g * 8;
        u16* op1 = op0 + P_PRED;
        uint4 o0, o1v;
        o0.x  = pack_bf16x2(acc[0].x, acc[1].x);
        o0.y  = pack_bf16x2(acc[2].x, acc[3].x);
        o0.z  = pack_bf16x2(acc[4].x, acc[5].x);
        o0.w  = pack_bf16x2(acc[6].x, acc[7].x);
        o1v.x = pack_bf16x2(acc[0].y, acc[1].y);
        o1v.y = pack_bf16x2(acc[2].y, acc[3].y);
        o1v.z = pack_bf16x2(acc[4].y, acc[5].y);
        o1v.w = pack_bf16x2(acc[6].y, acc[7].y);
        *(uint4*)op0 = o0;
        *(uint4*)op1 = o1v;
    } else {
        float* op0 = (float*)out_v + (size_t)(rowBase + q2) * P_PRED + g * 8;
        float* op1 = op0 + P_PRED;
        *(float4*)(op0)     = make_float4(acc[0].x, acc[1].x, acc[2].x, acc[3].x);
        *(float4*)(op0 + 4) = make_float4(acc[4].x, acc[5].x, acc[6].x, acc[7].x);
        *(float4*)(op1)     = make_float4(acc[0].y, acc[1].y, acc[2].y, acc[3].y);
        *(float4*)(op1 + 4) = make_float4(acc[4].y, acc[5].y, acc[6].y, acc[7].y);
    }
}

extern "C" void kernel_launch(void* const* d_in, const int* in_sizes, int n_in,
                              void* d_out, int out_size, void* d_ws, size_t ws_size,
                              hipStream_t stream_h) {
    const u32* clause_weights = (const u32*)d_in[1]; // bf16 or f32 [128]
    const u32* literal_idx    = (const u32*)d_in[2]; // int32 or int64 [128,3]
    const u32* sign_bits      = (const u32*)d_in[3]; // int32 or int64 [128,3]
    (void)d_ws; (void)ws_size;                       // workspace unused

    ke_fused<<<B_ROWS / RPB, TPB, 0, stream_h>>>(literal_idx, sign_bits,
                                                 clause_weights, d_in[0],
                                                 d_out);
}